// Round 6
// baseline (13419.641 us; speedup 1.0000x reference)
//
#include <hip/hip_runtime.h>
#include <stdint.h>

// Problem: B=1, L=2048, DIM=1536, H=12, HD=128. Inputs f32 (verified R1-R4).
// Output: f32 per harness doc (reference's output dtype). Torch convention
// (y = x @ W.T) exactly as the displayed reference. Naive correctness-first.
#define SEQ 2048
#define DIM 1536
#define NH  12
#define HD  128
#define SCALEF 0.08838834764831845f  // 128^-0.5

__device__ __forceinline__ float bf2f(unsigned short u) {
  return __uint_as_float(((unsigned int)u) << 16);
}
__device__ __forceinline__ float ldin(const void* p, size_t i, bool isbf) {
  return isbf ? bf2f(((const unsigned short*)p)[i]) : ((const float*)p)[i];
}

// Sentinel fill (structure-mismatch signaling), f32 pattern.
__global__ __launch_bounds__(256) void k_fill(float* __restrict__ out, int n,
                                              float val) {
  int i = blockIdx.x * 256 + threadIdx.x;
  if (i < n) out[i] = val;
}

// ---------------------------------------------------------------------------
// K0: per-input dtype detect (cheap insurance). flags[i]=1 -> bf16.
// ---------------------------------------------------------------------------
__global__ __launch_bounds__(256) void k_detect6(
    const void* p0, const void* p1, const void* p2, const void* p3,
    const void* p4, const void* p5, unsigned int* __restrict__ flags) {
  const void* ps[6] = {p0, p1, p2, p3, p4, p5};
  const unsigned int* x = (const unsigned int*)ps[blockIdx.x];
  __shared__ int cnt;
  if (threadIdx.x == 0) cnt = 0;
  __syncthreads();
  unsigned int w = x[threadIdx.x];
  int e = (w >> 7) & 0xFF;
  bool sane = (e >= 100 && e <= 140);
  unsigned long long b = __ballot(sane);
  if ((threadIdx.x & 63) == 0) atomicAdd(&cnt, (int)__popcll(b));
  __syncthreads();
  if (threadIdx.x == 0) flags[blockIdx.x] = (cnt >= 192) ? 1u : 0u;
}

// ---------------------------------------------------------------------------
// K1: GEMM, torch convention: C[m][n] = sum_c X[m][c] * W[n][c]. 32x32 tiles.
// ---------------------------------------------------------------------------
__global__ __launch_bounds__(256) void nk_gemm(
    const void* __restrict__ Xv, const void* __restrict__ W0,
    const void* __restrict__ W1, const void* __restrict__ W2,
    float* __restrict__ q, float* __restrict__ k, float* __restrict__ v,
    const unsigned int* __restrict__ fl) {
  __shared__ float As[32][33], Bs[32][33];
  int z = blockIdx.z;
  bool fx = fl[0] != 0u, fw = fl[1 + z] != 0u;
  const void* W = (z == 0) ? W0 : (z == 1) ? W1 : W2;
  float* C = (z == 0) ? q : (z == 1) ? k : v;
  int n0 = blockIdx.x * 32, m0 = blockIdx.y * 32;
  int t = threadIdx.x, tx = t & 15, ty = t >> 4;
  float acc00 = 0.f, acc01 = 0.f, acc10 = 0.f, acc11 = 0.f;
  for (int k0 = 0; k0 < DIM; k0 += 32) {
    __syncthreads();
#pragma unroll
    for (int i2 = 0; i2 < 4; i2++) {
      int e = i2 * 256 + t, r = e >> 5, c = e & 31;
      As[r][c] = ldin(Xv, (size_t)(m0 + r) * DIM + k0 + c, fx);
      Bs[r][c] = ldin(W, (size_t)(n0 + r) * DIM + k0 + c, fw);
    }
    __syncthreads();
#pragma unroll 8
    for (int c = 0; c < 32; c++) {
      float a0 = As[ty][c], a1 = As[ty + 16][c];
      float b0 = Bs[tx][c], b1 = Bs[tx + 16][c];
      acc00 += a0 * b0; acc01 += a0 * b1;
      acc10 += a1 * b0; acc11 += a1 * b1;
    }
  }
  C[(size_t)(m0 + ty) * DIM + n0 + tx] = acc00;
  C[(size_t)(m0 + ty) * DIM + n0 + tx + 16] = acc01;
  C[(size_t)(m0 + ty + 16) * DIM + n0 + tx] = acc10;
  C[(size_t)(m0 + ty + 16) * DIM + n0 + tx + 16] = acc11;
}

// ---------------------------------------------------------------------------
// K2: per-tensor amax of q/k/v.
// ---------------------------------------------------------------------------
__global__ __launch_bounds__(256) void nk_amax(
    const float* __restrict__ q, const float* __restrict__ k,
    const float* __restrict__ v, unsigned int* __restrict__ scal) {
  int z = blockIdx.y;
  const float* s = (z == 0) ? q : (z == 1) ? k : v;
  float m = 0.f;
  for (size_t i = (size_t)blockIdx.x * 256 + threadIdx.x; i < (size_t)SEQ * DIM;
       i += (size_t)gridDim.x * 256)
    m = fmaxf(m, fabsf(s[i]));
#pragma unroll
  for (int mk = 32; mk >= 1; mk >>= 1) m = fmaxf(m, __shfl_xor(m, mk, 64));
  __shared__ float sm[4];
  if ((threadIdx.x & 63) == 0) sm[threadIdx.x >> 6] = m;
  __syncthreads();
  if (threadIdx.x == 0) {
    m = fmaxf(fmaxf(sm[0], sm[1]), fmaxf(sm[2], sm[3]));
    atomicMax(&scal[z], __float_as_uint(m));
  }
}

// ---------------------------------------------------------------------------
// K3a: quantize q,k in place -> integer-valued f32.
// ---------------------------------------------------------------------------
__global__ __launch_bounds__(256) void nk_quant_qk(
    float* __restrict__ q, float* __restrict__ k,
    const unsigned int* __restrict__ scal) {
  int z = blockIdx.y;
  float* p = z ? k : q;
  float s = __uint_as_float(scal[z]) / 127.f;
  size_t i = ((size_t)blockIdx.x * 256 + threadIdx.x) * 4;
  float4 v = *(float4*)(p + i);
  v.x = fminf(fmaxf(rintf(v.x / s), -128.f), 127.f);
  v.y = fminf(fmaxf(rintf(v.y / s), -128.f), 127.f);
  v.z = fminf(fmaxf(rintf(v.z / s), -128.f), 127.f);
  v.w = fminf(fmaxf(rintf(v.w / s), -128.f), 127.f);
  *(float4*)(p + i) = v;
}

// ---------------------------------------------------------------------------
// K3b: quantize + transpose V -> vt[h*HD+d][k] (integer-valued f32).
// ---------------------------------------------------------------------------
__global__ __launch_bounds__(256) void nk_quant_vT(
    const float* __restrict__ v, float* __restrict__ vt,
    const unsigned int* __restrict__ scal) {
  float s = __uint_as_float(scal[2]) / 127.f;
  size_t idx = (size_t)blockIdx.x * 256 + threadIdx.x;  // over NH*HD*SEQ
  int k = (int)(idx & (SEQ - 1));
  int hd = (int)(idx >> 11);
  float x = v[(size_t)k * DIM + hd];
  vt[idx] = fminf(fmaxf(rintf(x / s), -128.f), 127.f);
}

// ---------------------------------------------------------------------------
// K4: per-row softmax stats (M, Z); global minZ -> max prob.
// ---------------------------------------------------------------------------
__global__ __launch_bounds__(256) void nk_stats(
    const float* __restrict__ q, const float* __restrict__ k,
    const unsigned int* __restrict__ scal, float* __restrict__ stats,
    unsigned int* __restrict__ minZ) {
  int h = blockIdx.y, i = blockIdx.x, t = threadIdx.x;
  float f = (__uint_as_float(scal[0]) / 127.f) *
            (__uint_as_float(scal[1]) / 127.f) * SCALEF;
  __shared__ float qrow[HD];
  if (t < HD) qrow[t] = q[(size_t)i * DIM + h * HD + t];
  __syncthreads();
  float sc[8], m = -3.4e38f;
#pragma unroll
  for (int j = 0; j < 8; j++) {
    int kr = j * 256 + t;
    const float* krow = k + (size_t)kr * DIM + h * HD;
    float s = 0.f;
    for (int d = 0; d < HD; d++) s += qrow[d] * krow[d];
    s *= f;
    sc[j] = s;
    m = fmaxf(m, s);
  }
#pragma unroll
  for (int mk = 32; mk >= 1; mk >>= 1) m = fmaxf(m, __shfl_xor(m, mk, 64));
  __shared__ float red[4];
  if ((t & 63) == 0) red[t >> 6] = m;
  __syncthreads();
  float M = fmaxf(fmaxf(red[0], red[1]), fmaxf(red[2], red[3]));
  float zl = 0.f;
#pragma unroll
  for (int j = 0; j < 8; j++) zl += expf(sc[j] - M);
#pragma unroll
  for (int mk = 32; mk >= 1; mk >>= 1) zl += __shfl_xor(zl, mk, 64);
  __shared__ float redz[4];
  if ((t & 63) == 0) redz[t >> 6] = zl;
  __syncthreads();
  if (t == 0) {
    float Z = redz[0] + redz[1] + redz[2] + redz[3];
    stats[((size_t)h * SEQ + i) * 2] = M;
    stats[((size_t)h * SEQ + i) * 2 + 1] = Z;
    atomicMin(minZ, __float_as_uint(Z));
  }
}

// ---------------------------------------------------------------------------
// K5: recompute scores -> quantized probs (LDS) -> PV. One block per (h, row).
// ---------------------------------------------------------------------------
__global__ __launch_bounds__(256) void nk_attn(
    const float* __restrict__ q, const float* __restrict__ k,
    const float* __restrict__ vt, const unsigned int* __restrict__ scal,
    const unsigned int* __restrict__ minZ, const float* __restrict__ stats,
    float* __restrict__ attn) {
  int h = blockIdx.y, i = blockIdx.x, t = threadIdx.x;
  float sq = __uint_as_float(scal[0]) / 127.f;
  float sk = __uint_as_float(scal[1]) / 127.f;
  float sv = __uint_as_float(scal[2]) / 127.f;
  float f = sq * sk * SCALEF;
  float sp = (1.f / __uint_as_float(*minZ)) / 127.f;
  float inv_sp = 1.f / sp;
  float M = stats[((size_t)h * SEQ + i) * 2];
  float invZ = 1.f / stats[((size_t)h * SEQ + i) * 2 + 1];
  __shared__ float qrow[HD];
  __shared__ float p[SEQ];
  if (t < HD) qrow[t] = q[(size_t)i * DIM + h * HD + t];
  __syncthreads();
#pragma unroll
  for (int j = 0; j < 8; j++) {
    int kr = j * 256 + t;
    const float* krow = k + (size_t)kr * DIM + h * HD;
    float s = 0.f;
    for (int d = 0; d < HD; d++) s += qrow[d] * krow[d];
    s *= f;
    float pr = expf(s - M) * invZ;
    p[kr] = fminf(rintf(pr * inv_sp), 127.f);
  }
  __syncthreads();
  int d = t & 127, half = t >> 7;
  const float* vrow = vt + (size_t)(h * HD + d) * SEQ + half * 1024;
  const float* ph = p + half * 1024;
  float acc = 0.f;
  for (int kk = 0; kk < 1024; kk++) acc += ph[kk] * vrow[kk];
  __shared__ float part[256];
  part[t] = acc;
  __syncthreads();
  if (t < 128)
    attn[(size_t)i * DIM + h * HD + d] = (part[t] + part[t + 128]) * sp * sv;
}

// ---------------------------------------------------------------------------
// K6: out-proj, torch conv: out[m][n] = sum_c A[m][c]*Wo[n][c] + bo[n]. f32.
// ---------------------------------------------------------------------------
__global__ __launch_bounds__(256) void nk_gemm_out(
    const float* __restrict__ A, const void* __restrict__ Wov,
    const void* __restrict__ bov, float* __restrict__ out,
    const unsigned int* __restrict__ fl) {
  __shared__ float As[32][33], Bs[32][33];
  bool fwo = fl[4] != 0u, fbo = fl[5] != 0u;
  int n0 = blockIdx.x * 32, m0 = blockIdx.y * 32;
  int t = threadIdx.x, tx = t & 15, ty = t >> 4;
  float acc00 = 0.f, acc01 = 0.f, acc10 = 0.f, acc11 = 0.f;
  for (int k0 = 0; k0 < DIM; k0 += 32) {
    __syncthreads();
#pragma unroll
    for (int i2 = 0; i2 < 4; i2++) {
      int e = i2 * 256 + t, r = e >> 5, c = e & 31;
      As[r][c] = A[(size_t)(m0 + r) * DIM + k0 + c];
      Bs[r][c] = ldin(Wov, (size_t)(n0 + r) * DIM + k0 + c, fwo);
    }
    __syncthreads();
#pragma unroll 8
    for (int c = 0; c < 32; c++) {
      float a0 = As[ty][c], a1 = As[ty + 16][c];
      float b0 = Bs[tx][c], b1 = Bs[tx + 16][c];
      acc00 += a0 * b0; acc01 += a0 * b1;
      acc10 += a1 * b0; acc11 += a1 * b1;
    }
  }
  float b0 = ldin(bov, n0 + tx, fbo), b1 = ldin(bov, n0 + tx + 16, fbo);
  out[(size_t)(m0 + ty) * DIM + n0 + tx] = acc00 + b0;
  out[(size_t)(m0 + ty) * DIM + n0 + tx + 16] = acc01 + b1;
  out[(size_t)(m0 + ty + 16) * DIM + n0 + tx] = acc10 + b0;
  out[(size_t)(m0 + ty + 16) * DIM + n0 + tx + 16] = acc11 + b1;
}

// ---------------------------------------------------------------------------
extern "C" void kernel_launch(void* const* d_in, const int* in_sizes, int n_in,
                              void* d_out, int out_size, void* d_ws, size_t ws_size,
                              hipStream_t stream) {
  float* out = (float*)d_out;
  bool sizes_ok = (n_in >= 6) && in_sizes && in_sizes[0] == SEQ * DIM &&
                  in_sizes[1] == DIM * DIM && in_sizes[2] == DIM * DIM &&
                  in_sizes[3] == DIM * DIM && in_sizes[4] == DIM * DIM &&
                  in_sizes[5] == DIM && out_size == SEQ * DIM;
  if (!sizes_ok) {
    k_fill<<<(out_size + 255) / 256, 256, 0, stream>>>(out, out_size, 1.0f);
    return;
  }
  if (ws_size < 50528296) {
    k_fill<<<(out_size + 255) / 256, 256, 0, stream>>>(out, out_size, 2.0f);
    return;
  }

  const void* x  = d_in[0];
  const void* Wq = d_in[1];
  const void* Wk = d_in[2];
  const void* Wv = d_in[3];
  const void* Wo = d_in[4];
  const void* bo = d_in[5];
  char* ws = (char*)d_ws;

  float* qf   = (float*)(ws);                      // 12582912 B
  float* kf   = (float*)(ws + 12582912);           // 12582912 B
  float* vf   = (float*)(ws + 25165824);           // 12582912 B
  float* vt   = (float*)(ws + 37748736);           // 12582912 B [NH*HD][SEQ]
  float* attn = vf;  // vf dead after nk_quant_vT
  float* stats = (float*)(ws + 50331648);          // 196608 B
  unsigned int* scal = (unsigned int*)(ws + 50528256);
  // scal[0..2]=amax q,k,v; scal[3]=minZ; scal[4..9]=per-input dtype flags

  hipMemsetAsync(scal, 0, 12, stream);
  hipMemsetAsync(scal + 3, 0x7f, 4, stream);  // minZ init ~3.39e38

  k_detect6<<<6, 256, 0, stream>>>(x, Wq, Wk, Wv, Wo, bo, scal + 4);
  nk_gemm<<<dim3(DIM / 32, SEQ / 32, 3), 256, 0, stream>>>(
      x, Wq, Wk, Wv, qf, kf, vf, scal + 4);
  nk_amax<<<dim3(512, 3), 256, 0, stream>>>(qf, kf, vf, scal);
  nk_quant_qk<<<dim3((SEQ * DIM) / 1024, 2), 256, 0, stream>>>(qf, kf, scal);
  nk_quant_vT<<<dim3((NH * HD * SEQ) / 256), 256, 0, stream>>>(vf, vt, scal);
  nk_stats<<<dim3(SEQ, NH), 256, 0, stream>>>(qf, kf, scal, stats, scal + 3);
  nk_attn<<<dim3(SEQ, NH), 256, 0, stream>>>(qf, kf, vt, scal, scal + 3, stats,
                                             attn);
  nk_gemm_out<<<dim3(DIM / 32, SEQ / 32), 256, 0, stream>>>(attn, Wo, bo, out,
                                                            scal + 4);
}

// Round 7
// 701.126 us; speedup vs baseline: 19.1401x; 19.1401x over previous
//
#include <hip/hip_runtime.h>
#include <stdint.h>

// B=1, L=2048, DIM=1536, H=12, HD=128. Inputs f32, output f32 (verified R6).
// MFMA pipeline (validated R2<->R3 agreement) + split-precision bf16x2 GEMMs.
#define SEQ 2048
#define DIM 1536
#define NH  12
#define HD  128
#define SCALEF 0.08838834764831845f  // 128^-0.5
#define LDP 40  // padded LDS row stride (shorts) for GEMM tiles

typedef __attribute__((ext_vector_type(8))) short short8;
typedef __attribute__((ext_vector_type(4))) float floatx4;

#define MFMA16(a, b, c) __builtin_amdgcn_mfma_f32_16x16x32_bf16((a), (b), (c), 0, 0, 0)

__device__ __forceinline__ void async_cp16(const void* g, void* l) {
  __builtin_amdgcn_global_load_lds(
      (__attribute__((address_space(1))) unsigned int*)(g),
      (__attribute__((address_space(3))) unsigned int*)(l), 16, 0, 0);
}

__device__ __forceinline__ unsigned short f2bf(float f) {
  unsigned int u = __float_as_uint(f);
  u = (u + 0x7fff + ((u >> 16) & 1)) >> 16;  // RNE
  return (unsigned short)u;
}

// Split f32 x -> hi (truncated bf16) + lo (RNE bf16 of residual).
// x ~= hi + lo with ~2^-17 relative error; missing lo*lo term ~2^-16.
__device__ __forceinline__ void split8(const float* g, short8& h, short8& l) {
  float4 f0 = *(const float4*)g, f1 = *(const float4*)(g + 4);
  float x[8] = {f0.x, f0.y, f0.z, f0.w, f1.x, f1.y, f1.z, f1.w};
#pragma unroll
  for (int e = 0; e < 8; e++) {
    unsigned int u = __float_as_uint(x[e]);
    h[e] = (short)(u >> 16);
    float r = x[e] - __uint_as_float(u & 0xFFFF0000u);
    l[e] = (short)f2bf(r);
  }
}

__global__ __launch_bounds__(256) void k_fill(float* __restrict__ out, int n,
                                              float val) {
  int i = blockIdx.x * 256 + threadIdx.x;
  if (i < n) out[i] = val;
}

// ---------------------------------------------------------------------------
// K1: QKV projections, torch conv: C[m,n] = sum_c X[m,c]*W[n,c]. Split-MFMA
// (3 products), 128x128 tile, BK=32, f32 out + per-tensor amax.
// ---------------------------------------------------------------------------
__global__ __launch_bounds__(256) void k_gemm_qkv(
    const float* __restrict__ X, const float* __restrict__ Wq,
    const float* __restrict__ Wk, const float* __restrict__ Wv,
    float* __restrict__ qf, float* __restrict__ kf, float* __restrict__ vf,
    unsigned int* __restrict__ scal) {
  __shared__ __align__(16) unsigned short Ah[128 * LDP], Al[128 * LDP];
  __shared__ __align__(16) unsigned short Bh[128 * LDP], Bl[128 * LDP];
  int tid = threadIdx.x, z = blockIdx.z;
  const float* W = (z == 0) ? Wq : (z == 1) ? Wk : Wv;
  float* C = (z == 0) ? qf : (z == 1) ? kf : vf;
  int n0 = blockIdx.x * 128, m0 = blockIdx.y * 128;
  int lane = tid & 63, w = tid >> 6;
  int wr = w >> 1, wc = w & 1, lm = lane & 15, q = lane >> 4;

  floatx4 acc[4][4];
#pragma unroll
  for (int i = 0; i < 4; i++)
#pragma unroll
    for (int j = 0; j < 4; j++) acc[i][j] = (floatx4){0.f, 0.f, 0.f, 0.f};

  int rowA = tid >> 2, c8 = tid & 3;
  for (int k0 = 0; k0 < DIM; k0 += 32) {
    __syncthreads();
#pragma unroll
    for (int i = 0; i < 2; i++) {
      int r = i * 64 + rowA;
      short8 h, l;
      split8(X + (size_t)(m0 + r) * DIM + k0 + c8 * 8, h, l);
      *(short8*)(Ah + r * LDP + c8 * 8) = h;
      *(short8*)(Al + r * LDP + c8 * 8) = l;
      split8(W + (size_t)(n0 + r) * DIM + k0 + c8 * 8, h, l);
      *(short8*)(Bh + r * LDP + c8 * 8) = h;
      *(short8*)(Bl + r * LDP + c8 * 8) = l;
    }
    __syncthreads();
    short8 ah[4], al[4], bh[4], bl[4];
#pragma unroll
    for (int i = 0; i < 4; i++) {
      int r = wr * 64 + i * 16 + lm;
      ah[i] = *(const short8*)(Ah + r * LDP + q * 8);
      al[i] = *(const short8*)(Al + r * LDP + q * 8);
    }
#pragma unroll
    for (int j = 0; j < 4; j++) {
      int r = wc * 64 + j * 16 + lm;
      bh[j] = *(const short8*)(Bh + r * LDP + q * 8);
      bl[j] = *(const short8*)(Bl + r * LDP + q * 8);
    }
#pragma unroll
    for (int i = 0; i < 4; i++)
#pragma unroll
      for (int j = 0; j < 4; j++) {
        acc[i][j] = MFMA16(ah[i], bh[j], acc[i][j]);
        acc[i][j] = MFMA16(ah[i], bl[j], acc[i][j]);
        acc[i][j] = MFMA16(al[i], bh[j], acc[i][j]);
      }
  }
  float am = 0.f;
#pragma unroll
  for (int i = 0; i < 4; i++) {
    int row = m0 + wr * 64 + i * 16 + q * 4;
#pragma unroll
    for (int j = 0; j < 4; j++) {
      int col = n0 + wc * 64 + j * 16 + lm;
#pragma unroll
      for (int r = 0; r < 4; r++) {
        float v = acc[i][j][r];
        C[(size_t)(row + r) * DIM + col] = v;
        am = fmaxf(am, fabsf(v));
      }
    }
  }
#pragma unroll
  for (int mk = 32; mk >= 1; mk >>= 1) am = fmaxf(am, __shfl_xor(am, mk, 64));
  if (lane == 0) atomicMax(&scal[z], __float_as_uint(am));
}

// ---------------------------------------------------------------------------
// K2a: quantize + transpose V -> nvT[h][d][k] (bf16 integer values).
// ---------------------------------------------------------------------------
__global__ __launch_bounds__(256) void k_quant_vT(
    const float* __restrict__ vf, const unsigned int* __restrict__ scal,
    unsigned short* __restrict__ nvT) {
  __shared__ float T[64 * 65];
  int h = blockIdx.z, d0 = blockIdx.y * 64, k0 = blockIdx.x * 64;
  float s = __uint_as_float(scal[2]) / 127.f;
  int t = threadIdx.x;
#pragma unroll
  for (int i = 0; i < 16; i++) {
    int idx = i * 256 + t;
    int r = idx >> 6, c = idx & 63;
    float v = vf[(size_t)(k0 + r) * DIM + h * HD + d0 + c];
    T[r * 65 + c] = fminf(fmaxf(rintf(v / s), -128.f), 127.f);
  }
  __syncthreads();
#pragma unroll
  for (int i = 0; i < 16; i++) {
    int idx = i * 256 + t;
    int d = idx >> 6, r = idx & 63;
    nvT[(size_t)(h * HD + d0 + d) * SEQ + k0 + r] = f2bf(T[r * 65 + d]);
  }
}

// ---------------------------------------------------------------------------
// K2b: quantize q,k -> integer-valued bf16.
// ---------------------------------------------------------------------------
__global__ __launch_bounds__(256) void k_quant_qk(
    const float* __restrict__ qf, const float* __restrict__ kf,
    const unsigned int* __restrict__ scal,
    unsigned short* __restrict__ nq, unsigned short* __restrict__ nk) {
  int z = blockIdx.y;
  const float* src = z ? kf : qf;
  unsigned short* dst = z ? nk : nq;
  float s = __uint_as_float(scal[z]) / 127.f;
  size_t i = ((size_t)blockIdx.x * 256 + threadIdx.x) * 4;
  float4 v = *(const float4*)(src + i);
  ushort4 o;
  o.x = f2bf(fminf(fmaxf(rintf(v.x / s), -128.f), 127.f));
  o.y = f2bf(fminf(fmaxf(rintf(v.y / s), -128.f), 127.f));
  o.z = f2bf(fminf(fmaxf(rintf(v.z / s), -128.f), 127.f));
  o.w = f2bf(fminf(fmaxf(rintf(v.w / s), -128.f), 127.f));
  *(ushort4*)(dst + i) = o;
}

// ---------------------------------------------------------------------------
// K3: softmax stats via integer MFMA QK^T. Per row: M (scaled max), Z.
// Block = 128 rows (4 waves x 32), one head. Global minZ via atomicMin.
// ---------------------------------------------------------------------------
__global__ __launch_bounds__(256) void k_stats(
    const unsigned short* __restrict__ nq, const unsigned short* __restrict__ nk,
    const unsigned int* __restrict__ scal,
    float* __restrict__ stats, unsigned int* __restrict__ minZ) {
  __shared__ unsigned short Ks[32 * 128];
  int h = blockIdx.y, tid = threadIdx.x, lane = tid & 63, w = tid >> 6;
  int lm = lane & 15, q = lane >> 4;
  int mb = blockIdx.x * 128 + w * 32;
  float f = (__uint_as_float(scal[0]) / 127.f) *
            (__uint_as_float(scal[1]) / 127.f) * SCALEF;

  short8 aq[2][4];
#pragma unroll
  for (int mi = 0; mi < 2; mi++) {
    const unsigned short* qb = nq + (size_t)(mb + mi * 16 + lm) * DIM + h * HD + q * 8;
#pragma unroll
    for (int cc = 0; cc < 4; cc++) aq[mi][cc] = *(const short8*)(qb + cc * 32);
  }

  float M[2][4];
#pragma unroll
  for (int mi = 0; mi < 2; mi++)
#pragma unroll
    for (int r = 0; r < 4; r++) M[mi][r] = -3.0e38f;

  for (int kt = 0; kt < SEQ; kt += 32) {
    __syncthreads();
#pragma unroll
    for (int i = 0; i < 2; i++) {
      int ch = i * 256 + tid;
      async_cp16(nk + (size_t)(kt + (ch >> 4)) * DIM + h * HD + (ch & 15) * 8,
                 Ks + ch * 8);
    }
    __syncthreads();
    short8 bk[2][4];
#pragma unroll
    for (int st = 0; st < 2; st++)
#pragma unroll
      for (int cc = 0; cc < 4; cc++)
        bk[st][cc] = *(const short8*)(Ks + (st * 16 + lm) * 128 + cc * 32 + q * 8);
#pragma unroll
    for (int mi = 0; mi < 2; mi++)
#pragma unroll
      for (int st = 0; st < 2; st++) {
        floatx4 acc = (floatx4){0.f, 0.f, 0.f, 0.f};
#pragma unroll
        for (int cc = 0; cc < 4; cc++) acc = MFMA16(aq[mi][cc], bk[st][cc], acc);
#pragma unroll
        for (int r = 0; r < 4; r++) M[mi][r] = fmaxf(M[mi][r], acc[r]);
      }
  }
#pragma unroll
  for (int mk = 1; mk < 16; mk <<= 1)
#pragma unroll
    for (int mi = 0; mi < 2; mi++)
#pragma unroll
      for (int r = 0; r < 4; r++)
        M[mi][r] = fmaxf(M[mi][r], __shfl_xor(M[mi][r], mk, 64));
#pragma unroll
  for (int mi = 0; mi < 2; mi++)
#pragma unroll
    for (int r = 0; r < 4; r++) M[mi][r] *= f;

  float Zl[2][4];
#pragma unroll
  for (int mi = 0; mi < 2; mi++)
#pragma unroll
    for (int r = 0; r < 4; r++) Zl[mi][r] = 0.f;

  for (int kt = 0; kt < SEQ; kt += 32) {
    __syncthreads();
#pragma unroll
    for (int i = 0; i < 2; i++) {
      int ch = i * 256 + tid;
      async_cp16(nk + (size_t)(kt + (ch >> 4)) * DIM + h * HD + (ch & 15) * 8,
                 Ks + ch * 8);
    }
    __syncthreads();
    short8 bk[2][4];
#pragma unroll
    for (int st = 0; st < 2; st++)
#pragma unroll
      for (int cc = 0; cc < 4; cc++)
        bk[st][cc] = *(const short8*)(Ks + (st * 16 + lm) * 128 + cc * 32 + q * 8);
#pragma unroll
    for (int mi = 0; mi < 2; mi++)
#pragma unroll
      for (int st = 0; st < 2; st++) {
        floatx4 acc = (floatx4){0.f, 0.f, 0.f, 0.f};
#pragma unroll
        for (int cc = 0; cc < 4; cc++) acc = MFMA16(aq[mi][cc], bk[st][cc], acc);
#pragma unroll
        for (int r = 0; r < 4; r++) Zl[mi][r] += expf(acc[r] * f - M[mi][r]);
      }
  }
#pragma unroll
  for (int mk = 1; mk < 16; mk <<= 1)
#pragma unroll
    for (int mi = 0; mi < 2; mi++)
#pragma unroll
      for (int r = 0; r < 4; r++) Zl[mi][r] += __shfl_xor(Zl[mi][r], mk, 64);

  if (lm == 0) {
#pragma unroll
    for (int mi = 0; mi < 2; mi++)
#pragma unroll
      for (int r = 0; r < 4; r++) {
        int row = mb + mi * 16 + q * 4 + r;
        stats[((size_t)h * SEQ + row) * 2] = M[mi][r];
        stats[((size_t)h * SEQ + row) * 2 + 1] = Zl[mi][r];
        atomicMin(minZ, __float_as_uint(Zl[mi][r]));
      }
  }
}

// ---------------------------------------------------------------------------
// K4: pass 2 — recompute scores, quantize probs, PV matmul (all integer MFMA).
// ---------------------------------------------------------------------------
__global__ __launch_bounds__(256) void k_attn(
    const unsigned short* __restrict__ nq, const unsigned short* __restrict__ nk,
    const unsigned short* __restrict__ nvT,
    const unsigned int* __restrict__ scal, const unsigned int* __restrict__ minZ,
    const float* __restrict__ stats, float* __restrict__ attn) {
  __shared__ unsigned short Ks[32 * 128];
  __shared__ unsigned short Vs[128 * 32];
  __shared__ unsigned short Pl[4][2][16 * 40];
  int h = blockIdx.y, tid = threadIdx.x, lane = tid & 63, w = tid >> 6;
  int lm = lane & 15, q = lane >> 4;
  int mb = blockIdx.x * 128 + w * 32;
  float sv = __uint_as_float(scal[2]) / 127.f;
  float f = (__uint_as_float(scal[0]) / 127.f) *
            (__uint_as_float(scal[1]) / 127.f) * SCALEF;
  float sp = (1.f / __uint_as_float(*minZ)) / 127.f;
  float inv_sp = 1.f / sp;

  short8 aq[2][4];
#pragma unroll
  for (int mi = 0; mi < 2; mi++) {
    const unsigned short* qb = nq + (size_t)(mb + mi * 16 + lm) * DIM + h * HD + q * 8;
#pragma unroll
    for (int cc = 0; cc < 4; cc++) aq[mi][cc] = *(const short8*)(qb + cc * 32);
  }
  float M[2][4], invZ[2][4];
#pragma unroll
  for (int mi = 0; mi < 2; mi++)
#pragma unroll
    for (int r = 0; r < 4; r++) {
      int row = mb + mi * 16 + q * 4 + r;
      M[mi][r] = stats[((size_t)h * SEQ + row) * 2];
      invZ[mi][r] = 1.f / stats[((size_t)h * SEQ + row) * 2 + 1];
    }
  floatx4 accO[2][8];
#pragma unroll
  for (int mi = 0; mi < 2; mi++)
#pragma unroll
    for (int j = 0; j < 8; j++) accO[mi][j] = (floatx4){0.f, 0.f, 0.f, 0.f};

  for (int kt = 0; kt < SEQ; kt += 32) {
    __syncthreads();
#pragma unroll
    for (int i = 0; i < 2; i++) {
      int ch = i * 256 + tid;
      async_cp16(nk + (size_t)(kt + (ch >> 4)) * DIM + h * HD + (ch & 15) * 8,
                 Ks + ch * 8);
      async_cp16(nvT + (size_t)(h * HD + (ch >> 2)) * SEQ + kt + (ch & 3) * 8,
                 Vs + ch * 8);
    }
    __syncthreads();
    short8 bk[2][4];
#pragma unroll
    for (int st = 0; st < 2; st++)
#pragma unroll
      for (int cc = 0; cc < 4; cc++)
        bk[st][cc] = *(const short8*)(Ks + (st * 16 + lm) * 128 + cc * 32 + q * 8);
#pragma unroll
    for (int mi = 0; mi < 2; mi++)
#pragma unroll
      for (int st = 0; st < 2; st++) {
        floatx4 acc = (floatx4){0.f, 0.f, 0.f, 0.f};
#pragma unroll
        for (int cc = 0; cc < 4; cc++) acc = MFMA16(aq[mi][cc], bk[st][cc], acc);
#pragma unroll
        for (int r = 0; r < 4; r++) {
          float t = expf(acc[r] * f - M[mi][r]);
          float n = rintf(t * invZ[mi][r] * inv_sp);
          n = fminf(n, 127.f);
          Pl[w][mi][(q * 4 + r) * 40 + st * 16 + lm] = f2bf(n);
        }
      }
    __syncthreads();
    short8 ap[2];
#pragma unroll
    for (int mi = 0; mi < 2; mi++)
      ap[mi] = *(const short8*)(&Pl[w][mi][lm * 40 + q * 8]);
#pragma unroll
    for (int j = 0; j < 8; j++) {
      short8 bv = *(const short8*)(Vs + (j * 16 + lm) * 32 + q * 8);
#pragma unroll
      for (int mi = 0; mi < 2; mi++) accO[mi][j] = MFMA16(ap[mi], bv, accO[mi][j]);
    }
  }
  float osc = sp * sv;
#pragma unroll
  for (int mi = 0; mi < 2; mi++)
#pragma unroll
    for (int j = 0; j < 8; j++)
#pragma unroll
      for (int r = 0; r < 4; r++)
        attn[(size_t)(mb + mi * 16 + q * 4 + r) * DIM + h * HD + j * 16 + lm] =
            accO[mi][j][r] * osc;
}

// ---------------------------------------------------------------------------
// K5: out-proj: out[m,n] = sum_c A[m,c]*Wo[n,c] + bo[n]. Split-MFMA, f32 out.
// ---------------------------------------------------------------------------
__global__ __launch_bounds__(256) void k_gemm_out(
    const float* __restrict__ A, const float* __restrict__ Wo,
    const float* __restrict__ bo, float* __restrict__ out) {
  __shared__ __align__(16) unsigned short Ah[128 * LDP], Al[128 * LDP];
  __shared__ __align__(16) unsigned short Bh[128 * LDP], Bl[128 * LDP];
  int tid = threadIdx.x;
  int n0 = blockIdx.x * 128, m0 = blockIdx.y * 128;
  int lane = tid & 63, w = tid >> 6;
  int wr = w >> 1, wc = w & 1, lm = lane & 15, q = lane >> 4;

  floatx4 acc[4][4];
#pragma unroll
  for (int i = 0; i < 4; i++)
#pragma unroll
    for (int j = 0; j < 4; j++) acc[i][j] = (floatx4){0.f, 0.f, 0.f, 0.f};

  int rowA = tid >> 2, c8 = tid & 3;
  for (int k0 = 0; k0 < DIM; k0 += 32) {
    __syncthreads();
#pragma unroll
    for (int i = 0; i < 2; i++) {
      int r = i * 64 + rowA;
      short8 h, l;
      split8(A + (size_t)(m0 + r) * DIM + k0 + c8 * 8, h, l);
      *(short8*)(Ah + r * LDP + c8 * 8) = h;
      *(short8*)(Al + r * LDP + c8 * 8) = l;
      split8(Wo + (size_t)(n0 + r) * DIM + k0 + c8 * 8, h, l);
      *(short8*)(Bh + r * LDP + c8 * 8) = h;
      *(short8*)(Bl + r * LDP + c8 * 8) = l;
    }
    __syncthreads();
    short8 ah[4], al[4], bh[4], bl[4];
#pragma unroll
    for (int i = 0; i < 4; i++) {
      int r = wr * 64 + i * 16 + lm;
      ah[i] = *(const short8*)(Ah + r * LDP + q * 8);
      al[i] = *(const short8*)(Al + r * LDP + q * 8);
    }
#pragma unroll
    for (int j = 0; j < 4; j++) {
      int r = wc * 64 + j * 16 + lm;
      bh[j] = *(const short8*)(Bh + r * LDP + q * 8);
      bl[j] = *(const short8*)(Bl + r * LDP + q * 8);
    }
#pragma unroll
    for (int i = 0; i < 4; i++)
#pragma unroll
      for (int j = 0; j < 4; j++) {
        acc[i][j] = MFMA16(ah[i], bh[j], acc[i][j]);
        acc[i][j] = MFMA16(ah[i], bl[j], acc[i][j]);
        acc[i][j] = MFMA16(al[i], bh[j], acc[i][j]);
      }
  }
#pragma unroll
  for (int j = 0; j < 4; j++) {
    int col = n0 + wc * 64 + j * 16 + lm;
    float bias = bo[col];
#pragma unroll
    for (int i = 0; i < 4; i++) {
      int row = m0 + wr * 64 + i * 16 + q * 4;
#pragma unroll
      for (int r = 0; r < 4; r++)
        out[(size_t)(row + r) * DIM + col] = acc[i][j][r] + bias;
    }
  }
}

// ---------------------------------------------------------------------------
extern "C" void kernel_launch(void* const* d_in, const int* in_sizes, int n_in,
                              void* d_out, int out_size, void* d_ws, size_t ws_size,
                              hipStream_t stream) {
  float* out = (float*)d_out;
  bool sizes_ok = (n_in >= 6) && in_sizes && in_sizes[0] == SEQ * DIM &&
                  in_sizes[1] == DIM * DIM && in_sizes[2] == DIM * DIM &&
                  in_sizes[3] == DIM * DIM && in_sizes[4] == DIM * DIM &&
                  in_sizes[5] == DIM && out_size == SEQ * DIM;
  if (!sizes_ok) {
    k_fill<<<(out_size + 255) / 256, 256, 0, stream>>>(out, out_size, 1.0f);
    return;
  }
  if (ws_size < 50528272) {
    k_fill<<<(out_size + 255) / 256, 256, 0, stream>>>(out, out_size, 2.0f);
    return;
  }

  const float* x  = (const float*)d_in[0];
  const float* Wq = (const float*)d_in[1];
  const float* Wk = (const float*)d_in[2];
  const float* Wv = (const float*)d_in[3];
  const float* Wo = (const float*)d_in[4];
  const float* bo = (const float*)d_in[5];
  char* ws = (char*)d_ws;

  // Workspace (peak 50.53 MB, fits the R6-validated bound):
  float* qf = (float*)(ws);                                // 12,582,912 B
  float* kf = (float*)(ws + 12582912);                     // 12,582,912 B
  float* vf = (float*)(ws + 25165824);                     // 12,582,912 B
  unsigned short* nvT = (unsigned short*)(ws + 37748736);  // 6,291,456 B
  unsigned short* nq  = (unsigned short*)(ws + 25165824);  // aliases vf (dead)
  unsigned short* nk  = (unsigned short*)(ws + 44040192);  // 6,291,456 B
  float* attn = qf;                                        // aliases qf (dead)
  float* stats = (float*)(ws + 50331648);                  // 196,608 B
  unsigned int* scal = (unsigned int*)(ws + 50528256);     // 16 B

  hipMemsetAsync(scal, 0, 12, stream);
  hipMemsetAsync(scal + 3, 0x7f, 4, stream);  // minZ init ~3.39e38

  k_gemm_qkv<<<dim3(DIM / 128, SEQ / 128, 3), 256, 0, stream>>>(
      x, Wq, Wk, Wv, qf, kf, vf, scal);
  k_quant_vT<<<dim3(SEQ / 64, HD / 64, NH), 256, 0, stream>>>(vf, scal, nvT);
  k_quant_qk<<<dim3((SEQ * DIM) / 1024, 2), 256, 0, stream>>>(qf, kf, scal, nq, nk);
  k_stats<<<dim3(SEQ / 128, NH), 256, 0, stream>>>(nq, nk, scal, stats, scal + 3);
  k_attn<<<dim3(SEQ / 128, NH), 256, 0, stream>>>(nq, nk, nvT, scal, scal + 3,
                                                  stats, attn);
  k_gemm_out<<<dim3(DIM / 128, SEQ / 128), 256, 0, stream>>>(attn, Wo, bo, out);
}

// Round 8
// 521.215 us; speedup vs baseline: 25.7469x; 1.3452x over previous
//
#include <hip/hip_runtime.h>
#include <stdint.h>

// B=1, L=2048, DIM=1536, H=12, HD=128. Inputs f32, output f32 (verified R6).
// R8: split-K parallelism (stats x8, attn x2), xor-swizzled LDS (bank-conflict
// free), single-sweep online softmax stats.
#define SEQ 2048
#define DIM 1536
#define NH  12
#define HD  128
#define SCALEF 0.08838834764831845f  // 128^-0.5
#define LDP 40  // padded LDS row stride (shorts) for GEMM tiles

typedef __attribute__((ext_vector_type(8))) short short8;
typedef __attribute__((ext_vector_type(4))) float floatx4;

#define MFMA16(a, b, c) __builtin_amdgcn_mfma_f32_16x16x32_bf16((a), (b), (c), 0, 0, 0)

__device__ __forceinline__ void async_cp16(const void* g, void* l) {
  __builtin_amdgcn_global_load_lds(
      (__attribute__((address_space(1))) unsigned int*)(g),
      (__attribute__((address_space(3))) unsigned int*)(l), 16, 0, 0);
}

__device__ __forceinline__ unsigned short f2bf(float f) {
  unsigned int u = __float_as_uint(f);
  u = (u + 0x7fff + ((u >> 16) & 1)) >> 16;  // RNE
  return (unsigned short)u;
}

// Split f32 -> hi (truncated bf16) + lo (RNE bf16 of residual).
__device__ __forceinline__ void split8v(const float* x, short8& h, short8& l) {
#pragma unroll
  for (int e = 0; e < 8; e++) {
    unsigned int u = __float_as_uint(x[e]);
    h[e] = (short)(u >> 16);
    float r = x[e] - __uint_as_float(u & 0xFFFF0000u);
    l[e] = (short)f2bf(r);
  }
}
__device__ __forceinline__ void split8(const float* g, short8& h, short8& l) {
  float4 f0 = *(const float4*)g, f1 = *(const float4*)(g + 4);
  float x[8] = {f0.x, f0.y, f0.z, f0.w, f1.x, f1.y, f1.z, f1.w};
  split8v(x, h, l);
}

__global__ __launch_bounds__(256) void k_fill(float* __restrict__ out, int n,
                                              float val) {
  int i = blockIdx.x * 256 + threadIdx.x;
  if (i < n) out[i] = val;
}

// ---------------------------------------------------------------------------
// K1: QKV projections: C[m,n] = sum_c X[m,c]*W[n,c]. Split-MFMA, 128x128 tile.
// ---------------------------------------------------------------------------
__global__ __launch_bounds__(256) void k_gemm_qkv(
    const float* __restrict__ X, const float* __restrict__ Wq,
    const float* __restrict__ Wk, const float* __restrict__ Wv,
    float* __restrict__ qf, float* __restrict__ kf, float* __restrict__ vf,
    unsigned int* __restrict__ scal) {
  __shared__ __align__(16) unsigned short Ah[128 * LDP], Al[128 * LDP];
  __shared__ __align__(16) unsigned short Bh[128 * LDP], Bl[128 * LDP];
  int tid = threadIdx.x, z = blockIdx.z;
  const float* W = (z == 0) ? Wq : (z == 1) ? Wk : Wv;
  float* C = (z == 0) ? qf : (z == 1) ? kf : vf;
  int n0 = blockIdx.x * 128, m0 = blockIdx.y * 128;
  int lane = tid & 63, w = tid >> 6;
  int wr = w >> 1, wc = w & 1, lm = lane & 15, q = lane >> 4;

  floatx4 acc[4][4];
#pragma unroll
  for (int i = 0; i < 4; i++)
#pragma unroll
    for (int j = 0; j < 4; j++) acc[i][j] = (floatx4){0.f, 0.f, 0.f, 0.f};

  int rowA = tid >> 2, c8 = tid & 3;
  for (int k0 = 0; k0 < DIM; k0 += 32) {
    __syncthreads();
#pragma unroll
    for (int i = 0; i < 2; i++) {
      int r = i * 64 + rowA;
      short8 h, l;
      split8(X + (size_t)(m0 + r) * DIM + k0 + c8 * 8, h, l);
      *(short8*)(Ah + r * LDP + c8 * 8) = h;
      *(short8*)(Al + r * LDP + c8 * 8) = l;
      split8(W + (size_t)(n0 + r) * DIM + k0 + c8 * 8, h, l);
      *(short8*)(Bh + r * LDP + c8 * 8) = h;
      *(short8*)(Bl + r * LDP + c8 * 8) = l;
    }
    __syncthreads();
    short8 ah[4], al[4], bh[4], bl[4];
#pragma unroll
    for (int i = 0; i < 4; i++) {
      int r = wr * 64 + i * 16 + lm;
      ah[i] = *(const short8*)(Ah + r * LDP + q * 8);
      al[i] = *(const short8*)(Al + r * LDP + q * 8);
    }
#pragma unroll
    for (int j = 0; j < 4; j++) {
      int r = wc * 64 + j * 16 + lm;
      bh[j] = *(const short8*)(Bh + r * LDP + q * 8);
      bl[j] = *(const short8*)(Bl + r * LDP + q * 8);
    }
#pragma unroll
    for (int i = 0; i < 4; i++)
#pragma unroll
      for (int j = 0; j < 4; j++) {
        acc[i][j] = MFMA16(ah[i], bh[j], acc[i][j]);
        acc[i][j] = MFMA16(ah[i], bl[j], acc[i][j]);
        acc[i][j] = MFMA16(al[i], bh[j], acc[i][j]);
      }
  }
  float am = 0.f;
#pragma unroll
  for (int i = 0; i < 4; i++) {
    int row = m0 + wr * 64 + i * 16 + q * 4;
#pragma unroll
    for (int j = 0; j < 4; j++) {
      int col = n0 + wc * 64 + j * 16 + lm;
#pragma unroll
      for (int r = 0; r < 4; r++) {
        float v = acc[i][j][r];
        C[(size_t)(row + r) * DIM + col] = v;
        am = fmaxf(am, fabsf(v));
      }
    }
  }
#pragma unroll
  for (int mk = 32; mk >= 1; mk >>= 1) am = fmaxf(am, __shfl_xor(am, mk, 64));
  if (lane == 0) atomicMax(&scal[z], __float_as_uint(am));
}

// ---------------------------------------------------------------------------
// K2a: quantize + transpose V -> nvT[h][d][k] (bf16 integer values).
// ---------------------------------------------------------------------------
__global__ __launch_bounds__(256) void k_quant_vT(
    const float* __restrict__ vf, const unsigned int* __restrict__ scal,
    unsigned short* __restrict__ nvT) {
  __shared__ float T[64 * 65];
  int h = blockIdx.z, d0 = blockIdx.y * 64, k0 = blockIdx.x * 64;
  float s = __uint_as_float(scal[2]) / 127.f;
  int t = threadIdx.x;
#pragma unroll
  for (int i = 0; i < 16; i++) {
    int idx = i * 256 + t;
    int r = idx >> 6, c = idx & 63;
    float v = vf[(size_t)(k0 + r) * DIM + h * HD + d0 + c];
    T[r * 65 + c] = fminf(fmaxf(rintf(v / s), -128.f), 127.f);
  }
  __syncthreads();
#pragma unroll
  for (int i = 0; i < 16; i++) {
    int idx = i * 256 + t;
    int d = idx >> 6, r = idx & 63;
    nvT[(size_t)(h * HD + d0 + d) * SEQ + k0 + r] = f2bf(T[r * 65 + d]);
  }
}

// ---------------------------------------------------------------------------
// K2b: quantize q,k -> integer-valued bf16.
// ---------------------------------------------------------------------------
__global__ __launch_bounds__(256) void k_quant_qk(
    const float* __restrict__ qf, const float* __restrict__ kf,
    const unsigned int* __restrict__ scal,
    unsigned short* __restrict__ nq, unsigned short* __restrict__ nk) {
  int z = blockIdx.y;
  const float* src = z ? kf : qf;
  unsigned short* dst = z ? nk : nq;
  float s = __uint_as_float(scal[z]) / 127.f;
  size_t i = ((size_t)blockIdx.x * 256 + threadIdx.x) * 4;
  float4 v = *(const float4*)(src + i);
  ushort4 o;
  o.x = f2bf(fminf(fmaxf(rintf(v.x / s), -128.f), 127.f));
  o.y = f2bf(fminf(fmaxf(rintf(v.y / s), -128.f), 127.f));
  o.z = f2bf(fminf(fmaxf(rintf(v.z / s), -128.f), 127.f));
  o.w = f2bf(fminf(fmaxf(rintf(v.w / s), -128.f), 127.f));
  *(ushort4*)(dst + i) = o;
}

// ---------------------------------------------------------------------------
// K3: partial softmax stats, split-K x8, online per-lane (m,z), swizzled Ks.
// Grid: (8*16, NH). pstats[h][row][chunk][2].
// ---------------------------------------------------------------------------
__global__ __launch_bounds__(256) void k_stats(
    const unsigned short* __restrict__ nq, const unsigned short* __restrict__ nk,
    const unsigned int* __restrict__ scal, float* __restrict__ pstats) {
  __shared__ unsigned short Ks[32 * 128];
  int h = blockIdx.y, tid = threadIdx.x, lane = tid & 63, w = tid >> 6;
  int lm = lane & 15, q = lane >> 4;
  int qb = blockIdx.x & 15, chunk = blockIdx.x >> 4;
  int mb = qb * 128 + w * 32;
  int kbase = chunk * 256;
  float f = (__uint_as_float(scal[0]) / 127.f) *
            (__uint_as_float(scal[1]) / 127.f) * SCALEF;

  short8 aq[2][4];
#pragma unroll
  for (int mi = 0; mi < 2; mi++) {
    const unsigned short* qb_p =
        nq + (size_t)(mb + mi * 16 + lm) * DIM + h * HD + q * 8;
#pragma unroll
    for (int cc = 0; cc < 4; cc++) aq[mi][cc] = *(const short8*)(qb_p + cc * 32);
  }

  float m[2][4], zz[2][4];
#pragma unroll
  for (int mi = 0; mi < 2; mi++)
#pragma unroll
    for (int r = 0; r < 4; r++) { m[mi][r] = -3.0e38f; zz[mi][r] = 0.f; }

  for (int kt = kbase; kt < kbase + 256; kt += 32) {
    __syncthreads();
#pragma unroll
    for (int i = 0; i < 2; i++) {
      int ch = i * 256 + tid;
      int krow = ch >> 4;
      int gcol = (ch & 15) ^ (krow & 7);  // xor-swizzle source column
      async_cp16(nk + (size_t)(kt + krow) * DIM + h * HD + gcol * 8,
                 Ks + ch * 8);
    }
    __syncthreads();
    short8 bk[2][4];
#pragma unroll
    for (int st = 0; st < 2; st++)
#pragma unroll
      for (int cc = 0; cc < 4; cc++) {
        int phys = (cc * 4 + q) ^ (lm & 7);
        bk[st][cc] = *(const short8*)(Ks + (st * 16 + lm) * 128 + phys * 8);
      }
#pragma unroll
    for (int mi = 0; mi < 2; mi++) {
      floatx4 a0 = (floatx4){0.f, 0.f, 0.f, 0.f};
      floatx4 a1 = (floatx4){0.f, 0.f, 0.f, 0.f};
#pragma unroll
      for (int cc = 0; cc < 4; cc++) {
        a0 = MFMA16(aq[mi][cc], bk[0][cc], a0);
        a1 = MFMA16(aq[mi][cc], bk[1][cc], a1);
      }
#pragma unroll
      for (int r = 0; r < 4; r++) {
        float s0 = a0[r] * f, s1 = a1[r] * f;
        float nm = fmaxf(m[mi][r], fmaxf(s0, s1));
        zz[mi][r] = zz[mi][r] * expf(m[mi][r] - nm) + expf(s0 - nm) +
                    expf(s1 - nm);
        m[mi][r] = nm;
      }
    }
  }
  // merge (m,z) across the 16 lanes sharing each row
#pragma unroll
  for (int mk = 1; mk < 16; mk <<= 1)
#pragma unroll
    for (int mi = 0; mi < 2; mi++)
#pragma unroll
      for (int r = 0; r < 4; r++) {
        float om = __shfl_xor(m[mi][r], mk, 64);
        float oz = __shfl_xor(zz[mi][r], mk, 64);
        float nm = fmaxf(m[mi][r], om);
        zz[mi][r] = zz[mi][r] * expf(m[mi][r] - nm) + oz * expf(om - nm);
        m[mi][r] = nm;
      }
  if (lm == 0) {
#pragma unroll
    for (int mi = 0; mi < 2; mi++)
#pragma unroll
      for (int r = 0; r < 4; r++) {
        int row = mb + mi * 16 + q * 4 + r;
        float* p = pstats + (((size_t)h * SEQ + row) * 8 + chunk) * 2;
        p[0] = m[mi][r];
        p[1] = zz[mi][r];
      }
  }
}

// ---------------------------------------------------------------------------
// K3b: merge 8 partial stats per row -> stats[h][row][2], global minZ.
// ---------------------------------------------------------------------------
__global__ __launch_bounds__(256) void k_merge(
    const float* __restrict__ pstats, float* __restrict__ stats,
    unsigned int* __restrict__ minZ) {
  int idx = blockIdx.x * 256 + threadIdx.x;  // h*SEQ + row
  const float* p = pstats + (size_t)idx * 16;
  float M = -3.0e38f;
#pragma unroll
  for (int c = 0; c < 8; c++) M = fmaxf(M, p[c * 2]);
  float Z = 0.f;
#pragma unroll
  for (int c = 0; c < 8; c++) Z += p[c * 2 + 1] * expf(p[c * 2] - M);
  stats[(size_t)idx * 2] = M;
  stats[(size_t)idx * 2 + 1] = Z;
  atomicMin(minZ, __float_as_uint(Z));
}

// ---------------------------------------------------------------------------
// K4: pass 2 — scores, quantize probs, PV. Split-K x2 -> partial O buffers.
// Grid: (2*16, NH). Swizzled Ks and Vs.
// ---------------------------------------------------------------------------
__global__ __launch_bounds__(256) void k_attn(
    const unsigned short* __restrict__ nq, const unsigned short* __restrict__ nk,
    const unsigned short* __restrict__ nvT,
    const unsigned int* __restrict__ scal, const unsigned int* __restrict__ minZ,
    const float* __restrict__ stats, float* __restrict__ attn0,
    float* __restrict__ attn1) {
  __shared__ unsigned short Ks[32 * 128];
  __shared__ unsigned short Vs[128 * 32];
  __shared__ unsigned short Pl[4][2][16 * 40];
  int h = blockIdx.y, tid = threadIdx.x, lane = tid & 63, w = tid >> 6;
  int lm = lane & 15, q = lane >> 4;
  int qb = blockIdx.x & 15, chunk = blockIdx.x >> 4;
  int mb = qb * 128 + w * 32;
  float* attn = chunk ? attn1 : attn0;
  float sv = __uint_as_float(scal[2]) / 127.f;
  float f = (__uint_as_float(scal[0]) / 127.f) *
            (__uint_as_float(scal[1]) / 127.f) * SCALEF;
  float sp = (1.f / __uint_as_float(*minZ)) / 127.f;
  float inv_sp = 1.f / sp;

  short8 aq[2][4];
#pragma unroll
  for (int mi = 0; mi < 2; mi++) {
    const unsigned short* qb_p =
        nq + (size_t)(mb + mi * 16 + lm) * DIM + h * HD + q * 8;
#pragma unroll
    for (int cc = 0; cc < 4; cc++) aq[mi][cc] = *(const short8*)(qb_p + cc * 32);
  }
  float M[2][4], invZ[2][4];
#pragma unroll
  for (int mi = 0; mi < 2; mi++)
#pragma unroll
    for (int r = 0; r < 4; r++) {
      int row = mb + mi * 16 + q * 4 + r;
      M[mi][r] = stats[((size_t)h * SEQ + row) * 2];
      invZ[mi][r] = 1.f / stats[((size_t)h * SEQ + row) * 2 + 1];
    }
  floatx4 accO[2][8];
#pragma unroll
  for (int mi = 0; mi < 2; mi++)
#pragma unroll
    for (int j = 0; j < 8; j++) accO[mi][j] = (floatx4){0.f, 0.f, 0.f, 0.f};

  int kbase = chunk * 1024;
  for (int kt = kbase; kt < kbase + 1024; kt += 32) {
    __syncthreads();
#pragma unroll
    for (int i = 0; i < 2; i++) {
      int ch = i * 256 + tid;
      int krow = ch >> 4;
      int gcol = (ch & 15) ^ (krow & 7);
      async_cp16(nk + (size_t)(kt + krow) * DIM + h * HD + gcol * 8,
                 Ks + ch * 8);
      int d = ch >> 2;
      int vcol = (ch & 3) ^ ((d >> 1) & 3);
      async_cp16(nvT + (size_t)(h * HD + d) * SEQ + kt + vcol * 8,
                 Vs + ch * 8);
    }
    __syncthreads();
    short8 bk[2][4];
#pragma unroll
    for (int st = 0; st < 2; st++)
#pragma unroll
      for (int cc = 0; cc < 4; cc++) {
        int phys = (cc * 4 + q) ^ (lm & 7);
        bk[st][cc] = *(const short8*)(Ks + (st * 16 + lm) * 128 + phys * 8);
      }
#pragma unroll
    for (int mi = 0; mi < 2; mi++)
#pragma unroll
      for (int st = 0; st < 2; st++) {
        floatx4 acc = (floatx4){0.f, 0.f, 0.f, 0.f};
#pragma unroll
        for (int cc = 0; cc < 4; cc++) acc = MFMA16(aq[mi][cc], bk[st][cc], acc);
#pragma unroll
        for (int r = 0; r < 4; r++) {
          float t = expf(acc[r] * f - M[mi][r]);
          float n = rintf(t * invZ[mi][r] * inv_sp);
          n = fminf(n, 127.f);
          Pl[w][mi][(q * 4 + r) * 40 + st * 16 + lm] = f2bf(n);
        }
      }
    __syncthreads();
    short8 ap[2];
#pragma unroll
    for (int mi = 0; mi < 2; mi++)
      ap[mi] = *(const short8*)(&Pl[w][mi][lm * 40 + q * 8]);
#pragma unroll
    for (int j = 0; j < 8; j++) {
      int d = j * 16 + lm;
      int vphys = q ^ ((d >> 1) & 3);
      short8 bv = *(const short8*)(Vs + d * 32 + vphys * 8);
#pragma unroll
      for (int mi = 0; mi < 2; mi++) accO[mi][j] = MFMA16(ap[mi], bv, accO[mi][j]);
    }
  }
  float osc = sp * sv;
#pragma unroll
  for (int mi = 0; mi < 2; mi++)
#pragma unroll
    for (int j = 0; j < 8; j++)
#pragma unroll
      for (int r = 0; r < 4; r++)
        attn[(size_t)(mb + mi * 16 + q * 4 + r) * DIM + h * HD + j * 16 + lm] =
            accO[mi][j][r] * osc;
}

// ---------------------------------------------------------------------------
// K5: out-proj: out[m,n] = sum_c (A0+A1)[m,c]*Wo[n,c] + bo[n]. Split-MFMA.
// ---------------------------------------------------------------------------
__global__ __launch_bounds__(256) void k_gemm_out(
    const float* __restrict__ A0, const float* __restrict__ A1,
    const float* __restrict__ Wo, const float* __restrict__ bo,
    float* __restrict__ out) {
  __shared__ __align__(16) unsigned short Ah[128 * LDP], Al[128 * LDP];
  __shared__ __align__(16) unsigned short Bh[128 * LDP], Bl[128 * LDP];
  int tid = threadIdx.x;
  int n0 = blockIdx.x * 128, m0 = blockIdx.y * 128;
  int lane = tid & 63, w = tid >> 6;
  int wr = w >> 1, wc = w & 1, lm = lane & 15, q = lane >> 4;

  floatx4 acc[4][4];
#pragma unroll
  for (int i = 0; i < 4; i++)
#pragma unroll
    for (int j = 0; j < 4; j++) acc[i][j] = (floatx4){0.f, 0.f, 0.f, 0.f};

  int rowA = tid >> 2, c8 = tid & 3;
  for (int k0 = 0; k0 < DIM; k0 += 32) {
    __syncthreads();
#pragma unroll
    for (int i = 0; i < 2; i++) {
      int r = i * 64 + rowA;
      size_t off = (size_t)(m0 + r) * DIM + k0 + c8 * 8;
      float4 x0 = *(const float4*)(A0 + off), x1 = *(const float4*)(A0 + off + 4);
      float4 y0 = *(const float4*)(A1 + off), y1 = *(const float4*)(A1 + off + 4);
      float xs[8] = {x0.x + y0.x, x0.y + y0.y, x0.z + y0.z, x0.w + y0.w,
                     x1.x + y1.x, x1.y + y1.y, x1.z + y1.z, x1.w + y1.w};
      short8 h, l;
      split8v(xs, h, l);
      *(short8*)(Ah + r * LDP + c8 * 8) = h;
      *(short8*)(Al + r * LDP + c8 * 8) = l;
      split8(Wo + (size_t)(n0 + r) * DIM + k0 + c8 * 8, h, l);
      *(short8*)(Bh + r * LDP + c8 * 8) = h;
      *(short8*)(Bl + r * LDP + c8 * 8) = l;
    }
    __syncthreads();
    short8 ah[4], al[4], bh[4], bl[4];
#pragma unroll
    for (int i = 0; i < 4; i++) {
      int r = wr * 64 + i * 16 + lm;
      ah[i] = *(const short8*)(Ah + r * LDP + q * 8);
      al[i] = *(const short8*)(Al + r * LDP + q * 8);
    }
#pragma unroll
    for (int j = 0; j < 4; j++) {
      int r = wc * 64 + j * 16 + lm;
      bh[j] = *(const short8*)(Bh + r * LDP + q * 8);
      bl[j] = *(const short8*)(Bl + r * LDP + q * 8);
    }
#pragma unroll
    for (int i = 0; i < 4; i++)
#pragma unroll
      for (int j = 0; j < 4; j++) {
        acc[i][j] = MFMA16(ah[i], bh[j], acc[i][j]);
        acc[i][j] = MFMA16(ah[i], bl[j], acc[i][j]);
        acc[i][j] = MFMA16(al[i], bh[j], acc[i][j]);
      }
  }
#pragma unroll
  for (int j = 0; j < 4; j++) {
    int col = n0 + wc * 64 + j * 16 + lm;
    float bias = bo[col];
#pragma unroll
    for (int i = 0; i < 4; i++) {
      int row = m0 + wr * 64 + i * 16 + q * 4;
#pragma unroll
      for (int r = 0; r < 4; r++)
        out[(size_t)(row + r) * DIM + col] = acc[i][j][r] + bias;
    }
  }
}

// ---------------------------------------------------------------------------
extern "C" void kernel_launch(void* const* d_in, const int* in_sizes, int n_in,
                              void* d_out, int out_size, void* d_ws, size_t ws_size,
                              hipStream_t stream) {
  float* out = (float*)d_out;
  bool sizes_ok = (n_in >= 6) && in_sizes && in_sizes[0] == SEQ * DIM &&
                  in_sizes[1] == DIM * DIM && in_sizes[2] == DIM * DIM &&
                  in_sizes[3] == DIM * DIM && in_sizes[4] == DIM * DIM &&
                  in_sizes[5] == DIM && out_size == SEQ * DIM;
  if (!sizes_ok) {
    k_fill<<<(out_size + 255) / 256, 256, 0, stream>>>(out, out_size, 1.0f);
    return;
  }
  if (ws_size < 50528272) {
    k_fill<<<(out_size + 255) / 256, 256, 0, stream>>>(out, out_size, 2.0f);
    return;
  }

  const float* x  = (const float*)d_in[0];
  const float* Wq = (const float*)d_in[1];
  const float* Wk = (const float*)d_in[2];
  const float* Wv = (const float*)d_in[3];
  const float* Wo = (const float*)d_in[4];
  const float* bo = (const float*)d_in[5];
  char* ws = (char*)d_ws;

  // Workspace layout (peak < 50.53 MB):
  float* qf = (float*)(ws);                                // 12,582,912 B
  float* kf = (float*)(ws + 12582912);                     // 12,582,912 B
  float* vf = (float*)(ws + 25165824);                     // 12,582,912 B
  unsigned short* nq  = (unsigned short*)(ws + 25165824);  // aliases vf (dead)
  float* pstats = (float*)(ws + 31457280);                 // 1,572,864 B
  unsigned short* nvT = (unsigned short*)(ws + 37748736);  // 6,291,456 B
  unsigned short* nk  = (unsigned short*)(ws + 44040192);  // 6,291,456 B
  float* attn0 = qf;                                       // aliases qf (dead)
  float* attn1 = kf;                                       // aliases kf (dead)
  float* stats = (float*)(ws + 50331648);                  // 196,608 B
  unsigned int* scal = (unsigned int*)(ws + 50528256);     // 16 B

  hipMemsetAsync(scal, 0, 12, stream);
  hipMemsetAsync(scal + 3, 0x7f, 4, stream);  // minZ init ~3.39e38

  k_gemm_qkv<<<dim3(DIM / 128, SEQ / 128, 3), 256, 0, stream>>>(
      x, Wq, Wk, Wv, qf, kf, vf, scal);
  k_quant_vT<<<dim3(SEQ / 64, HD / 64, NH), 256, 0, stream>>>(vf, scal, nvT);
  k_quant_qk<<<dim3((SEQ * DIM) / 1024, 2), 256, 0, stream>>>(qf, kf, scal, nq, nk);
  k_stats<<<dim3(8 * 16, NH), 256, 0, stream>>>(nq, nk, scal, pstats);
  k_merge<<<dim3(NH * SEQ / 256), 256, 0, stream>>>(pstats, stats, scal + 3);
  k_attn<<<dim3(2 * 16, NH), 256, 0, stream>>>(nq, nk, nvT, scal, scal + 3,
                                               stats, attn0, attn1);
  k_gemm_out<<<dim3(DIM / 128, SEQ / 128), 256, 0, stream>>>(attn0, attn1, Wo,
                                                             bo, out);
}